// Round 2
// baseline (144.500 us; speedup 1.0000x reference)
//
#include <hip/hip_runtime.h>

// RelationAwareDiscriminator:
//   out[b,u,v] = sigmoid( sum_{d,e} UE[u,d] * R[r[b],d,e] * VE[v,e] )
// Dedup: out[b] depends on b only via r[b] (64 distinct relations).
// Compute each (rel, u-tile, v-tile) tile ONCE, replicate to matching b's.

#define BATCH 512
#define DIM   128
#define NRELS 64
#define UTILE 64
#define VTILE 64
#define NTHR  256

typedef float floatx4 __attribute__((ext_vector_type(4)));

__global__ __launch_bounds__(NTHR, 2)
void rad_fused_kernel(const int* __restrict__ u_idx,
                      const int* __restrict__ v_idx,
                      const int* __restrict__ r_idx,
                      const float* __restrict__ nodes,   // [100000][128]
                      const float* __restrict__ rels,    // [64][128][128]
                      float* __restrict__ out)           // [512][512][512]
{
    const int rel = (int)blockIdx.x >> 3;          // 0..63
    const int ut0 = ((int)blockIdx.x & 7) * UTILE; // 0..448

    __shared__ int s_match[BATCH];
    __shared__ int s_mc;
    __shared__ __align__(16) float s_TsT[DIM * UTILE];           // [e][u], 32 KB
    __shared__ __align__(16) float s_buf[DIM * UTILE + 16 * DIM]; // 40 KB scratch

    const int t  = (int)threadIdx.x;
    const int tu = t >> 4;   // 0..15 (u group of 4)
    const int tx = t & 15;   // 0..15 (e/v group)

    if (t == 0) s_mc = 0;
    __syncthreads();
    // Build list of batch indices b with r[b] == rel.
    for (int i = t; i < BATCH; i += NTHR) {
        if (r_idx[i] == rel) {
            int p = atomicAdd(&s_mc, 1);
            s_match[p] = i;
        }
    }

    float* UEsT = s_buf;               // [d][u] 128x64, 32 KB
    float* Rs   = s_buf + DIM * UTILE; // [dd][e] 16x128, 8 KB

    // Gather u-embedding rows, store transposed [d][u].
    for (int i = t; i < UTILE * (DIM / 4); i += NTHR) {
        const int row = i & (UTILE - 1);
        const int dc  = i >> 6; // 0..31
        const float4 val = *reinterpret_cast<const float4*>(
            nodes + (size_t)u_idx[ut0 + row] * DIM + dc * 4);
        UEsT[(dc * 4 + 0) * UTILE + row] = val.x;
        UEsT[(dc * 4 + 1) * UTILE + row] = val.y;
        UEsT[(dc * 4 + 2) * UTILE + row] = val.z;
        UEsT[(dc * 4 + 3) * UTILE + row] = val.w;
    }
    __syncthreads();
    const int mc = s_mc;
    if (mc == 0) return; // relation absent from batch: nothing to write

    // ---------------- Phase A: TsT[e][u] = sum_d UEsT[d][u] * R[rel][d][e]
    float accA[4][8];
    #pragma unroll
    for (int i = 0; i < 4; ++i)
        #pragma unroll
        for (int j = 0; j < 8; ++j) accA[i][j] = 0.f;

    const float* Rbase = rels + (size_t)rel * DIM * DIM;
    for (int dch = 0; dch < DIM / 16; ++dch) {
        // Stage 16 rows of R into LDS (coalesced float4).
        for (int i = t; i < 16 * (DIM / 4); i += NTHR) {
            const int rr = i >> 5;  // 0..15
            const int cc = i & 31;  // 0..31
            *reinterpret_cast<float4*>(Rs + rr * DIM + cc * 4) =
                *reinterpret_cast<const float4*>(
                    Rbase + (size_t)(dch * 16 + rr) * DIM + cc * 4);
        }
        __syncthreads();
        #pragma unroll
        for (int dd = 0; dd < 16; ++dd) {
            const int d = dch * 16 + dd;
            const float4 a  = *reinterpret_cast<const float4*>(UEsT + d * UTILE + tu * 4);
            const float4 b0 = *reinterpret_cast<const float4*>(Rs + dd * DIM + tx * 4);
            const float4 b1 = *reinterpret_cast<const float4*>(Rs + dd * DIM + 64 + tx * 4);
            const float av[4] = {a.x, a.y, a.z, a.w};
            const float bv[8] = {b0.x, b0.y, b0.z, b0.w, b1.x, b1.y, b1.z, b1.w};
            #pragma unroll
            for (int i = 0; i < 4; ++i)
                #pragma unroll
                for (int j = 0; j < 8; ++j)
                    accA[i][j] = fmaf(av[i], bv[j], accA[i][j]);
        }
        __syncthreads();
    }

    // Write TsT[e][u].
    #pragma unroll
    for (int j = 0; j < 8; ++j) {
        const int e = (j < 4) ? (tx * 4 + j) : (64 + tx * 4 + (j - 4));
        #pragma unroll
        for (int i = 0; i < 4; ++i)
            s_TsT[e * UTILE + tu * 4 + i] = accA[i][j];
    }

    // ---------------- Phase B: per v-chunk, score tile + sigmoid + replicate
    float* VEsT = s_buf; // [e][v] 128x64, reuses scratch (32 KB)
    for (int vt = 0; vt < BATCH / VTILE; ++vt) {
        __syncthreads(); // prev chunk's VEsT reads done; TsT visible (1st iter)
        for (int i = t; i < VTILE * (DIM / 4); i += NTHR) {
            const int row = i & (VTILE - 1);
            const int ec  = i >> 6;
            const float4 val = *reinterpret_cast<const float4*>(
                nodes + (size_t)v_idx[vt * VTILE + row] * DIM + ec * 4);
            VEsT[(ec * 4 + 0) * VTILE + row] = val.x;
            VEsT[(ec * 4 + 1) * VTILE + row] = val.y;
            VEsT[(ec * 4 + 2) * VTILE + row] = val.z;
            VEsT[(ec * 4 + 3) * VTILE + row] = val.w;
        }
        __syncthreads();

        float acc[4][4];
        #pragma unroll
        for (int i = 0; i < 4; ++i)
            #pragma unroll
            for (int j = 0; j < 4; ++j) acc[i][j] = 0.f;

        #pragma unroll 8
        for (int e = 0; e < DIM; ++e) {
            const float4 a = *reinterpret_cast<const float4*>(s_TsT + e * UTILE + tu * 4);
            const float4 b = *reinterpret_cast<const float4*>(VEsT  + e * VTILE + tx * 4);
            const float av[4] = {a.x, a.y, a.z, a.w};
            const float bv[4] = {b.x, b.y, b.z, b.w};
            #pragma unroll
            for (int i = 0; i < 4; ++i)
                #pragma unroll
                for (int j = 0; j < 4; ++j)
                    acc[i][j] = fmaf(av[i], bv[j], acc[i][j]);
        }

        // sigmoid -> native ext_vector for nontemporal stores
        floatx4 sg[4];
        #pragma unroll
        for (int i = 0; i < 4; ++i) {
            sg[i].x = 1.f / (1.f + __expf(-acc[i][0]));
            sg[i].y = 1.f / (1.f + __expf(-acc[i][1]));
            sg[i].z = 1.f / (1.f + __expf(-acc[i][2]));
            sg[i].w = 1.f / (1.f + __expf(-acc[i][3]));
        }

        // Replicate the tile to every b with r[b] == rel (nontemporal: the
        // 537 MB output stream must not thrash L2).
        for (int m = 0; m < mc; ++m) {
            const int bb = s_match[m];
            float* obase = out + (size_t)bb * BATCH * BATCH;
            #pragma unroll
            for (int i = 0; i < 4; ++i) {
                floatx4* dst = reinterpret_cast<floatx4*>(
                    obase + (size_t)(ut0 + tu * 4 + i) * BATCH + vt * VTILE + tx * 4);
                __builtin_nontemporal_store(sg[i], dst);
            }
        }
    }
}

extern "C" void kernel_launch(void* const* d_in, const int* in_sizes, int n_in,
                              void* d_out, int out_size, void* d_ws, size_t ws_size,
                              hipStream_t stream) {
    const int*   u_idx = (const int*)d_in[0];
    const int*   v_idx = (const int*)d_in[1];
    const int*   r_idx = (const int*)d_in[2];
    const float* nodes = (const float*)d_in[3];
    const float* rels  = (const float*)d_in[4];
    float* out = (float*)d_out;

    dim3 grid(NRELS * (BATCH / UTILE)); // 64 rels x 8 u-tiles = 512 blocks
    dim3 block(NTHR);
    rad_fused_kernel<<<grid, block, 0, stream>>>(u_idx, v_idx, r_idx, nodes, rels, out);
}